// Round 7
// baseline (224.527 us; speedup 1.0000x reference)
//
#include <hip/hip_runtime.h>
#include <hip/hip_bf16.h>

// Conv_SelfAttn — B=8, C=128, N=4096, C_QK=16. fp32 in/out.
// Round 11:
//  attn: remove the ch-split duplication. Wave = (kr 0..3, qh 0..1); each
//        wave computes QK+softmax ONCE per key chunk and does full-C PV
//        (acc 64 f32). Block = 64 queries, grid 512 = exactly 2 blocks/CU
//        co-resident -> single scheduling round, no tail.
//        Total MFMA -21%, exp2 -50%, K bytes -50% vs round 10.
//  qkv:  unchanged (round-10 5-wave). Gap theory: fixed overhead, not qkv.
//
// Layout assumptions (32x32x16_bf16):
//   C/D: col = lane&31, row = (reg&3) + 8*(reg>>2) + 4*(lane>>5)   [m74/m101]
//   A  : m  = lane&31, k = 8*(lane>>5) + j (j=0..7 contiguous)
//   B  : n  = lane&31, k = 8*(lane>>5) + j
//
// ws (all bf16):
//   qw [B][128 tile][f(hi/lo)][lq][lr][8]   (2 MB, log2e pre-scaled)
//   kw [B][128 chunk][f(hi/lo)][lq][lr][8]  (2 MB)
//   vw [B][128 chunk][ct(4)][f(2)][lq][lr][8] (8 MB), key axis kappa-permuted

typedef __bf16 bf16x8 __attribute__((ext_vector_type(8)));
typedef __bf16 bf16x4 __attribute__((ext_vector_type(4)));
typedef float  f32x16 __attribute__((ext_vector_type(16)));

static constexpr int Bb = 8, Cc = 128, Nn = 4096, CQ = 16;

__device__ __forceinline__ f32x16 mfma32(bf16x8 a, bf16x8 b, f32x16 c) {
    return __builtin_amdgcn_mfma_f32_32x32x16_bf16(a, b, c, 0, 0, 0);
}
struct HL { __bf16 h, l; };
__device__ __forceinline__ HL hilo(float f) {
    HL r;
    r.h = (__bf16)f;
    r.l = (__bf16)(f - (float)r.h);
    return r;
}

// ---------------- Kernel 1: QKV projection (MFMA) ----------------
// grid (N/32, B), 320 threads (5 waves). Per block: x-tile 128ci x 32n.
// Staging by threads 0..255; roles: w4 = QK, w0..w3 = V c-tile ct=wave.
__global__ __launch_bounds__(320) void qkv_kernel(
    const float* __restrict__ x, const float* __restrict__ Wq,
    const float* __restrict__ Wk, const float* __restrict__ Wv,
    __bf16* __restrict__ qw, __bf16* __restrict__ kw, __bf16* __restrict__ vw)
{
    const int b = blockIdx.y, tile = blockIdx.x, n0 = tile * 32, t = threadIdx.x;
    const int wave = t >> 6, lane = t & 63, lr = lane & 31, lq = lane >> 5;

    __shared__ __bf16 xh[32][136], xl[32][136];   // x^T tile (n-major), hi/lo
    __shared__ __bf16 sc[4][32][40];              // per-V-wave transpose scratch

    // stage x: thread owns (n = t&31, 16 consecutive ci). Coalesced-f32 reads.
    if (t < 256) {
        const int n = t & 31, ci0 = (t >> 5) * 16;
        float v[16];
        #pragma unroll
        for (int k = 0; k < 16; ++k)
            v[k] = x[((size_t)(b * Cc + ci0 + k)) * Nn + n0 + n];
        bf16x8 h8[2], l8[2];
        #pragma unroll
        for (int k = 0; k < 16; ++k) {
            HL z = hilo(v[k]);
            h8[k >> 3][k & 7] = z.h;
            l8[k >> 3][k & 7] = z.l;
        }
        *(bf16x8*)&xh[n][ci0]     = h8[0];
        *(bf16x8*)&xh[n][ci0 + 8] = h8[1];
        *(bf16x8*)&xl[n][ci0]     = l8[0];
        *(bf16x8*)&xl[n][ci0 + 8] = l8[1];
    }
    __syncthreads();

    if (wave == 4) {
        // ---- QK: A-frags direct from global, stacked [Wq;Wk] row lr ----
        const float* wrow = (lr < 16) ? (Wq + (size_t)lr * Cc)
                                      : (Wk + (size_t)(lr - 16) * Cc);
        f32x16 acc = {};
        #pragma unroll
        for (int ks = 0; ks < 8; ++ks) {
            float4 w0 = *(const float4*)(wrow + ks * 16 + lq * 8);
            float4 w1 = *(const float4*)(wrow + ks * 16 + lq * 8 + 4);
            bf16x8 ah, al;
            HL z;
            z = hilo(w0.x); ah[0] = z.h; al[0] = z.l;
            z = hilo(w0.y); ah[1] = z.h; al[1] = z.l;
            z = hilo(w0.z); ah[2] = z.h; al[2] = z.l;
            z = hilo(w0.w); ah[3] = z.h; al[3] = z.l;
            z = hilo(w1.x); ah[4] = z.h; al[4] = z.l;
            z = hilo(w1.y); ah[5] = z.h; al[5] = z.l;
            z = hilo(w1.z); ah[6] = z.h; al[6] = z.l;
            z = hilo(w1.w); ah[7] = z.h; al[7] = z.l;
            bf16x8 bh = *(const bf16x8*)&xh[lr][ks * 16 + lq * 8];
            bf16x8 bl = *(const bf16x8*)&xl[lr][ks * 16 + lq * 8];
            acc = mfma32(ah, bh, acc);
            acc = mfma32(al, bh, acc);
            acc = mfma32(ah, bl, acc);
        }
        // vectorized fragment-major stores: rg 0,1 -> q ; rg 2,3 -> k
        __bf16* qb = qw + (((size_t)b * 128 + tile) << 10);
        __bf16* kb = kw + (((size_t)b * 128 + tile) << 10);
        #pragma unroll
        for (int rg = 0; rg < 4; ++rg) {
            bf16x4 h4, l4;
            #pragma unroll
            for (int j = 0; j < 4; ++j) {
                float v = acc[rg * 4 + j];
                if (rg < 2) v *= 1.44269504089f;     // fold log2e into Q
                HL z = hilo(v);
                h4[j] = z.h; l4[j] = z.l;
            }
            const int off = (rg & 1) * 256 + lr * 8 + 4 * lq;
            __bf16* base = (rg < 2) ? qb : kb;
            *(bf16x4*)(base + off) = h4;
            *(bf16x4*)(base + 512 + off) = l4;
        }
    } else {
        // ---- V: one c-tile per wave; Wv fragments direct from global ----
        const int ct = wave;
        f32x16 acc = {};
        #pragma unroll
        for (int ks = 0; ks < 8; ++ks) {
            const float* wp = Wv + (size_t)(ct * 32 + lr) * Cc + ks * 16 + lq * 8;
            float4 w0 = *(const float4*)wp;
            float4 w1 = *(const float4*)(wp + 4);
            bf16x8 a = { (__bf16)w0.x, (__bf16)w0.y, (__bf16)w0.z, (__bf16)w0.w,
                         (__bf16)w1.x, (__bf16)w1.y, (__bf16)w1.z, (__bf16)w1.w };
            bf16x8 bh = *(const bf16x8*)&xh[lr][ks * 16 + lq * 8];
            acc = mfma32(a, bh, acc);
        }
        // transpose via wave-private LDS scratch, key axis kappa-permuted
        // (kappa = swap bits 2<->3) so attn's P needs no lane exchange.
        const int klr = (lr & ~12) | ((lr & 4) << 1) | ((lr & 8) >> 1);
        #pragma unroll
        for (int r = 0; r < 16; ++r) {
            int crow = (r & 3) + 8 * (r >> 2) + 4 * lq;
            sc[wave][crow][klr] = (__bf16)acc[r];
        }
        __bf16* vb = vw + (((size_t)b * 128 + tile) << 12) + ct * 1024;
        // dense 16B-per-lane stores: lane owns (f=u, lqK=lq, c=lr, j=0..7)
        #pragma unroll
        for (int u = 0; u < 2; ++u) {
            bf16x8 row = *(const bf16x8*)&sc[wave][lr][u * 16 + lq * 8];
            *(bf16x8*)(vb + u * 512 + lane * 8) = row;
        }
    }
}

// ---------------- Kernel 2: full-C per-wave flash attention ----------------
// grid 512 x 512 thr. Block -> (b = bid&7 [XCD-pinned], 64 queries).
// Wave w: kr = w&3 (key chunks kr*32..+32), qh = w>>2 (query subtile).
// Each wave: QK+softmax ONCE per chunk, full-C=128 PV (acc 64 f32).
// Fixed softmax max (m=0, exp2 domain). Key-permuted V -> identity P frags.
__global__ __launch_bounds__(512, 4) void attn_kernel(
    const float* __restrict__ x, const __bf16* __restrict__ qw,
    const __bf16* __restrict__ kw, const __bf16* __restrict__ vw,
    const float* __restrict__ gamma, float* __restrict__ out)
{
    const int h = blockIdx.x;
    const int b = h & 7;                 // consecutive blocks -> different XCDs
    const int qp = h >> 3;               // 64-query pair index (0..63)
    const int t = threadIdx.x;
    const int wave = t >> 6, lane = t & 63, lr = lane & 31, lq = lane >> 5;
    const int kr = wave & 3, qh = wave >> 2;

    __shared__ float accbuf[64][129];
    __shared__ float lbuf[64];

    // Q fragment (pre-split hi/lo, pre-scaled): dense 16B loads
    const int tile = qp * 2 + qh;        // 32-query tile index
    const __bf16* qb = qw + (((size_t)b * 128 + tile) << 10) + lane * 8;
    const bf16x8 qhi = *(const bf16x8*)qb;
    const bf16x8 qlo = *(const bf16x8*)(qb + 512);

    const int c0 = kr * 32;              // this wave's first key chunk
    const __bf16* kp = kw + (((size_t)b * 128 + c0) << 10) + lane * 8;
    const __bf16* vp = vw + (((size_t)b * 128 + c0) << 12) + lane * 8;

    f32x16 acc[4] = {{}, {}, {}, {}};
    float l_part = 0.f;

    // K register set A <- chunk c0; set B rotates (2x-unrolled loop)
    bf16x8 akh = *(const bf16x8*)kp, akl = *(const bf16x8*)(kp + 512);
    bf16x8 bkh, bkl;

    auto body = [&](const bf16x8& Kh, const bf16x8& Kl, const __bf16* vpc) {
        // issue this chunk's 8 V fragment loads first (covered by QK+softmax)
        bf16x8 v[8];
        #pragma unroll
        for (int u = 0; u < 8; ++u) v[u] = *(const bf16x8*)(vpc + u * 512);

        // S^T = K * Q^T (one 32x32 tile, hi/lo 3-term)
        f32x16 s = {};
        s = mfma32(Kh, qhi, s);
        s = mfma32(Kl, qhi, s);
        s = mfma32(Kh, qlo, s);

        // p = 2^s (log2 domain; fixed max)
        float p[16];
        #pragma unroll
        for (int r = 0; r < 16; ++r) p[r] = __builtin_amdgcn_exp2f(s[r]);
        l_part += ((((p[0] + p[1]) + (p[2] + p[3])) + ((p[4] + p[5]) + (p[6] + p[7])))
                 + (((p[8] + p[9]) + (p[10] + p[11])) + ((p[12] + p[13]) + (p[14] + p[15]))));

        // P fragments: identity order thanks to kappa-permuted V storage
        bf16x8 F0, F1;
        #pragma unroll
        for (int j = 0; j < 8; ++j) {
            F0[j] = (__bf16)p[j];
            F1[j] = (__bf16)p[8 + j];
        }

        // O^T += V^T * P (full C: 4 c-tiles)
        #pragma unroll
        for (int ct = 0; ct < 4; ++ct) {
            acc[ct] = mfma32(v[2 * ct],     F0, acc[ct]);
            acc[ct] = mfma32(v[2 * ct + 1], F1, acc[ct]);
        }
    };

    // 2x-unrolled main loop: 32 chunks = preload + 15x2 + 2 peeled
    for (int it = 0; it < 15; ++it) {
        kp += 1024;
        bkh = *(const bf16x8*)kp; bkl = *(const bf16x8*)(kp + 512);
        body(akh, akl, vp); vp += 4096;
        kp += 1024;
        akh = *(const bf16x8*)kp; akl = *(const bf16x8*)(kp + 512);
        body(bkh, bkl, vp); vp += 4096;
    }
    kp += 1024;
    bkh = *(const bf16x8*)kp; bkl = *(const bf16x8*)(kp + 512);
    body(akh, akl, vp); vp += 4096;      // chunk 30
    body(bkh, bkl, vp);                  // chunk 31

    // pair-sum of softmax denominator (each lane summed its 16-key half)
    l_part += __shfl_xor(l_part, 32);

    // -------- merge 4 kr-partials per query subtile (pure sums) --------
    const int qrow = qh * 32 + lr;
    if (kr == 0) {                       // waves (0,qh) init their 32 rows
        #pragma unroll
        for (int ct = 0; ct < 4; ++ct)
            #pragma unroll
            for (int r = 0; r < 16; ++r) {
                int c = (r & 3) + 8 * (r >> 2) + 4 * lq + 32 * ct;
                accbuf[qrow][c] = acc[ct][r];
            }
        if (lane < 32) lbuf[qrow] = l_part;
    }
    __syncthreads();
    if (kr != 0) {
        #pragma unroll
        for (int ct = 0; ct < 4; ++ct)
            #pragma unroll
            for (int r = 0; r < 16; ++r) {
                int c = (r & 3) + 8 * (r >> 2) + 4 * lq + 32 * ct;
                atomicAdd(&accbuf[qrow][c], acc[ct][r]);
            }
        if (lane < 32) atomicAdd(&lbuf[qrow], l_part);
    }
    __syncthreads();

    // -------- epilogue: out = x + gamma * O / l (coalesced along n) --------
    const float g = gamma[0];
    const int q = t & 63, cg = t >> 6;   // q 0..63, cg 0..7
    const float linv = 1.0f / lbuf[q];
    const int n0b = qp * 64;
    #pragma unroll
    for (int i = 0; i < 16; ++i) {
        int c = cg + 8 * i;
        size_t idx = ((size_t)(b * Cc + c)) * Nn + n0b + q;
        out[idx] = x[idx] + g * accbuf[q][c] * linv;
    }
}

extern "C" void kernel_launch(void* const* d_in, const int* in_sizes, int n_in,
                              void* d_out, int out_size, void* d_ws, size_t ws_size,
                              hipStream_t stream) {
    const float* x  = (const float*)d_in[0];
    const float* Wq = (const float*)d_in[1];
    const float* Wk = (const float*)d_in[2];
    const float* Wv = (const float*)d_in[3];
    const float* gm = (const float*)d_in[4];

    __bf16* qw = (__bf16*)d_ws;                        // 2 MB
    __bf16* kw = qw + (size_t)Bb * 128 * 1024;         // 2 MB
    __bf16* vw = kw + (size_t)Bb * 128 * 1024;         // 8 MB

    qkv_kernel<<<dim3(Nn / 32, Bb), 320, 0, stream>>>(x, Wq, Wk, Wv, qw, kw, vw);
    attn_kernel<<<dim3(Nn / 64 * Bb), 512, 0, stream>>>(x, qw, kw, vw, gm,
                                                        (float*)d_out);
}